// Round 1
// baseline (1213.600 us; speedup 1.0000x reference)
//
#include <hip/hip_runtime.h>

#define NN    2048
#define DIN   768
#define DOUT  1024
#define NH    8
#define HD    128
#define QKVW  3072
#define SCALEF 0.08838834764831845f
#define NEGF  (-1.0e9f)
#define EPSF  1e-5f

// workspace layout (float offsets)
#define OFF_QKV 0
#define OFF_GQ  (NN*QKVW)                 // 6291456
#define OFF_GK  (OFF_GQ + NN*NH)          // 6307840
#define OFF_MX  (OFF_GK + NN*NH)          // 6324224
#define OFF_INV (OFF_MX + NH*NN)          // 6340608
#define OFF_O   (OFF_INV + NH*NN)         // 6356992
#define OFF_YACC (OFF_O + NN*DOUT)        // 8454144
#define ZERO_COUNT (NN*DOUT + NN*DIN)     // 3670016 floats (O + YACC)

// ---------------- shared 128x128x16 SGEMM inner ----------------
__device__ __forceinline__ void mm_inner16(const float (*As)[132],
                                           const float (*Bs)[132],
                                           float (&acc)[8][8], int tx, int ty) {
#pragma unroll
  for (int k = 0; k < 16; ++k) {
    float a[8], b[8];
    *(float4*)&a[0] = *(const float4*)&As[k][ty * 8];
    *(float4*)&a[4] = *(const float4*)&As[k][ty * 8 + 4];
    *(float4*)&b[0] = *(const float4*)&Bs[k][tx * 8];
    *(float4*)&b[4] = *(const float4*)&Bs[k][tx * 8 + 4];
#pragma unroll
    for (int m = 0; m < 8; ++m)
#pragma unroll
      for (int n = 0; n < 8; ++n)
        acc[m][n] = fmaf(a[m], b[n], acc[m][n]);
  }
}

// ---------------- zero O + YACC ----------------
__global__ __launch_bounds__(256) void k_zero(float4* __restrict__ p) {
  p[(size_t)blockIdx.x * 256 + threadIdx.x] = float4{0.f, 0.f, 0.f, 0.f};
}

// ---------------- QKV projection: qkv[i, 0:3072] ----------------
__global__ __launch_bounds__(256) void k_qkv(const float* __restrict__ x,
                                             const float* __restrict__ wq,
                                             const float* __restrict__ wk,
                                             const float* __restrict__ wv,
                                             const float* __restrict__ bq,
                                             const float* __restrict__ bk,
                                             const float* __restrict__ bv,
                                             float* __restrict__ qkv) {
  const int n0 = blockIdx.x * 128;  // 0..2944
  const int i0 = blockIdx.y * 128;
  const int mat = n0 >> 10;
  const int c0 = n0 & 1023;
  const float* W = (mat == 0) ? wq : (mat == 1) ? wk : wv;
  const float* bias = (mat == 0) ? bq : (mat == 1) ? bk : bv;
  __shared__ __align__(16) float As[16][132];
  __shared__ __align__(16) float Bs[16][132];
  const int tid = threadIdx.x;
  const int tx = tid & 15, ty = tid >> 4;
  float acc[8][8] = {};
  for (int k0 = 0; k0 < DIN; k0 += 16) {
#pragma unroll
    for (int l = 0; l < 2; ++l) {
      int f = tid + l * 256;
      int row = f >> 2, kc = (f & 3) * 4;
      float4 va = *(const float4*)(x + (size_t)(i0 + row) * DIN + k0 + kc);
      As[kc + 0][row] = va.x; As[kc + 1][row] = va.y;
      As[kc + 2][row] = va.z; As[kc + 3][row] = va.w;
      int kr = f >> 5, c4 = (f & 31) * 4;
      float4 vb = *(const float4*)(W + (size_t)(k0 + kr) * DOUT + c0 + c4);
      *(float4*)&Bs[kr][c4] = vb;
    }
    __syncthreads();
    mm_inner16(As, Bs, acc, tx, ty);
    __syncthreads();
  }
#pragma unroll
  for (int m = 0; m < 8; ++m) {
    float o[8];
#pragma unroll
    for (int n = 0; n < 8; ++n) o[n] = acc[m][n] + bias[c0 + tx * 8 + n];
    float* dst = qkv + (size_t)(i0 + ty * 8 + m) * QKVW + n0 + tx * 8;
    *(float4*)dst = *(float4*)&o[0];
    *(float4*)(dst + 4) = *(float4*)&o[4];
  }
}

// ---------------- gating: gq/gk = tanh(q/k @ gw + gb)  [N,H] ----------------
__global__ __launch_bounds__(256) void k_gates(const float* __restrict__ QKV,
                                               const float* __restrict__ gqw,
                                               const float* __restrict__ gqb,
                                               const float* __restrict__ gkw,
                                               const float* __restrict__ gkb,
                                               float* __restrict__ GQ,
                                               float* __restrict__ GK) {
  const int i = blockIdx.x;
  const int tid = threadIdx.x;
  float aq[NH] = {}, ak[NH] = {};
  for (int d = tid; d < DOUT; d += 256) {
    float qv = QKV[(size_t)i * QKVW + d];
    float kv = QKV[(size_t)i * QKVW + DOUT + d];
#pragma unroll
    for (int h = 0; h < NH; ++h) {
      aq[h] = fmaf(qv, gqw[d * NH + h], aq[h]);
      ak[h] = fmaf(kv, gkw[d * NH + h], ak[h]);
    }
  }
  __shared__ float red8[NH][256];
#pragma unroll
  for (int h = 0; h < NH; ++h) red8[h][tid] = aq[h];
  __syncthreads();
  for (int s = 128; s > 0; s >>= 1) {
    if (tid < s) {
#pragma unroll
      for (int h = 0; h < NH; ++h) red8[h][tid] += red8[h][tid + s];
    }
    __syncthreads();
  }
  if (tid < NH) GQ[i * NH + tid] = tanhf(red8[tid][0] + gqb[tid]);
  __syncthreads();
#pragma unroll
  for (int h = 0; h < NH; ++h) red8[h][tid] = ak[h];
  __syncthreads();
  for (int s = 128; s > 0; s >>= 1) {
    if (tid < s) {
#pragma unroll
      for (int h = 0; h < NH; ++h) red8[h][tid] += red8[h][tid + s];
    }
    __syncthreads();
  }
  if (tid < NH) GK[i * NH + tid] = tanhf(red8[tid][0] + gkb[tid]);
}

// ---------------- scores: S[h,i,j] = masked (q.k)*SCALE -> ATTN ----------------
__global__ __launch_bounds__(256) void k_scores(const float* __restrict__ QKV,
                                                const int* __restrict__ batch,
                                                float* __restrict__ ATTN) {
  const int h = blockIdx.z;
  const int i0 = blockIdx.y * 128;
  const int j0 = blockIdx.x * 128;
  __shared__ __align__(16) float As[16][132];
  __shared__ __align__(16) float Bs[16][132];
  const int tid = threadIdx.x;
  const int tx = tid & 15, ty = tid >> 4;
  float acc[8][8] = {};
  const int qoff = h * HD;
  const int koff = DOUT + h * HD;
  for (int k0 = 0; k0 < HD; k0 += 16) {
#pragma unroll
    for (int l = 0; l < 2; ++l) {
      int f = tid + l * 256;
      int row = f >> 2, kc = (f & 3) * 4;
      float4 va = *(const float4*)(QKV + (size_t)(i0 + row) * QKVW + qoff + k0 + kc);
      As[kc + 0][row] = va.x; As[kc + 1][row] = va.y;
      As[kc + 2][row] = va.z; As[kc + 3][row] = va.w;
      float4 vb = *(const float4*)(QKV + (size_t)(j0 + row) * QKVW + koff + k0 + kc);
      Bs[kc + 0][row] = vb.x; Bs[kc + 1][row] = vb.y;
      Bs[kc + 2][row] = vb.z; Bs[kc + 3][row] = vb.w;
    }
    __syncthreads();
    mm_inner16(As, Bs, acc, tx, ty);
    __syncthreads();
  }
  int bi_[8], bj_[8];
#pragma unroll
  for (int m = 0; m < 8; ++m) bi_[m] = batch[i0 + ty * 8 + m];
#pragma unroll
  for (int n = 0; n < 8; ++n) bj_[n] = batch[j0 + tx * 8 + n];
#pragma unroll
  for (int m = 0; m < 8; ++m) {
    float o[8];
#pragma unroll
    for (int n = 0; n < 8; ++n)
      o[n] = (bi_[m] == bj_[n]) ? acc[m][n] * SCALEF : NEGF;
    float* dst = ATTN + ((size_t)(h * NN) + i0 + ty * 8 + m) * NN + j0 + tx * 8;
    *(float4*)dst = *(float4*)&o[0];
    *(float4*)(dst + 4) = *(float4*)&o[4];
  }
}

// ---------------- assemble attn_final in place (tile pairs) ----------------
#define TS 16
__global__ __launch_bounds__(256) void k_assemble(float* __restrict__ ATTN,
                                                  const float* __restrict__ motif,
                                                  const float* __restrict__ GQ,
                                                  const float* __restrict__ GK,
                                                  const float* __restrict__ Whead,
                                                  const float* __restrict__ alpha_p,
                                                  const float* __restrict__ beta_p) {
  const int bi = blockIdx.y, bj = blockIdx.x;
  if (bj < bi) return;
  const int i0 = bi * TS, j0 = bj * TS;
  __shared__ float Sij[NH][TS][TS + 1];
  __shared__ float Sji[NH][TS][TS + 1];
  __shared__ float mtA[TS][TS + 1];
  __shared__ float mtB[TS][TS + 1];
  __shared__ float sW[NH * NH];
  const int tid = threadIdx.x;
  const int c = tid & 15, r = tid >> 4;
#pragma unroll
  for (int h = 0; h < NH; ++h) {
    Sij[h][r][c] = ATTN[((size_t)(h * NN) + i0 + r) * NN + j0 + c];
    Sji[h][r][c] = ATTN[((size_t)(h * NN) + j0 + r) * NN + i0 + c];
  }
  if (tid < NH * NH) sW[tid] = Whead[tid];
  const float alpha = alpha_p[0], beta = beta_p[0];
  __syncthreads();
  for (int h = 0; h < NH; ++h) {
    mtA[r][c] = motif[((size_t)(h * NN) + j0 + r) * NN + i0 + c];
    mtB[r][c] = motif[((size_t)(h * NN) + i0 + r) * NN + j0 + c];
    __syncthreads();
    // tile A: output (h, i0+r, j0+c)
    {
      float s = Sij[h][r][c];
      float hm = 0.f;
#pragma unroll
      for (int h2 = 0; h2 < NH; ++h2) hm = fmaf(Sij[h2][r][c], sW[h2 * NH + h], hm);
      float outv = s + alpha * Sji[h][c][r] + beta * mtA[c][r] +
                   s * (GQ[(i0 + r) * NH + h] + GK[(j0 + c) * NH + h]) + hm;
      ATTN[((size_t)(h * NN) + i0 + r) * NN + j0 + c] = outv;
    }
    if (bi != bj) {  // tile B: output (h, j0+r, i0+c)
      float s = Sji[h][r][c];
      float hm = 0.f;
#pragma unroll
      for (int h2 = 0; h2 < NH; ++h2) hm = fmaf(Sji[h2][r][c], sW[h2 * NH + h], hm);
      float outv = s + alpha * Sij[h][c][r] + beta * mtB[c][r] +
                   s * (GQ[(j0 + r) * NH + h] + GK[(i0 + c) * NH + h]) + hm;
      ATTN[((size_t)(h * NN) + j0 + r) * NN + i0 + c] = outv;
    }
    __syncthreads();
  }
}

// ---------------- softmax stats per row ----------------
__global__ __launch_bounds__(256) void k_stats(const float* __restrict__ ATTN,
                                               float* __restrict__ MX,
                                               float* __restrict__ INVS) {
  const int row = blockIdx.x;  // 0..NH*NN-1
  const int tid = threadIdx.x;
  const float* p = ATTN + (size_t)row * NN;
  float v[8];
  float m = -3.4e38f;
#pragma unroll
  for (int t = 0; t < 8; ++t) {
    v[t] = p[tid + t * 256];
    m = fmaxf(m, v[t]);
  }
  __shared__ float red[256];
  red[tid] = m; __syncthreads();
  for (int s = 128; s > 0; s >>= 1) {
    if (tid < s) red[tid] = fmaxf(red[tid], red[tid + s]);
    __syncthreads();
  }
  m = red[0];
  __syncthreads();
  float sum = 0.f;
#pragma unroll
  for (int t = 0; t < 8; ++t) sum += expf(v[t] - m);
  red[tid] = sum; __syncthreads();
  for (int s = 128; s > 0; s >>= 1) {
    if (tid < s) red[tid] += red[tid + s];
    __syncthreads();
  }
  if (tid == 0) {
    MX[row] = m;
    INVS[row] = 1.0f / red[0];
  }
}

// ---------------- P@V with on-the-fly softmax, K-split + atomics ----------------
__global__ __launch_bounds__(256) void k_pv(const float* __restrict__ ATTN,
                                            const float* __restrict__ QKV,
                                            const float* __restrict__ MX,
                                            const float* __restrict__ INVS,
                                            float* __restrict__ O) {
  const int ks = blockIdx.x;       // j chunk of 512
  const int i0 = blockIdx.y * 128;
  const int h = blockIdx.z;
  const int jbase = ks * 512;
  __shared__ __align__(16) float As[16][132];
  __shared__ __align__(16) float Bs[16][132];
  const int tid = threadIdx.x;
  const int tx = tid & 15, ty = tid >> 4;
  float acc[8][8] = {};
  const int voff = 2 * DOUT + h * HD;
  for (int k0 = 0; k0 < 512; k0 += 16) {
#pragma unroll
    for (int l = 0; l < 2; ++l) {
      int f = tid + l * 256;
      int row = f >> 2, kc = (f & 3) * 4;
      size_t flat = (size_t)(h * NN) + i0 + row;
      float mx = MX[flat];
      float inv = INVS[flat];
      float4 va = *(const float4*)(ATTN + flat * NN + jbase + k0 + kc);
      As[kc + 0][row] = expf(va.x - mx) * inv;
      As[kc + 1][row] = expf(va.y - mx) * inv;
      As[kc + 2][row] = expf(va.z - mx) * inv;
      As[kc + 3][row] = expf(va.w - mx) * inv;
      int kr = f >> 5, c4 = (f & 31) * 4;
      float4 vb = *(const float4*)(QKV + (size_t)(jbase + k0 + kr) * QKVW + voff + c4);
      *(float4*)&Bs[kr][c4] = vb;
    }
    __syncthreads();
    mm_inner16(As, Bs, acc, tx, ty);
    __syncthreads();
  }
#pragma unroll
  for (int m = 0; m < 8; ++m)
#pragma unroll
    for (int n = 0; n < 8; ++n)
      atomicAdd(&O[(size_t)(i0 + ty * 8 + m) * DOUT + h * HD + tx * 8 + n], acc[m][n]);
}

// ---------------- out-proj GEMM (K-split + atomics into YACC) ----------------
__global__ __launch_bounds__(256) void k_outproj(const float* __restrict__ O,
                                                 const float* __restrict__ wo,
                                                 float* __restrict__ YACC) {
  const int n0 = blockIdx.x * 128;  // 0..640
  const int i0 = blockIdx.y * 128;
  const int kbase = blockIdx.z * 256;
  __shared__ __align__(16) float As[16][132];
  __shared__ __align__(16) float Bs[16][132];
  const int tid = threadIdx.x;
  const int tx = tid & 15, ty = tid >> 4;
  float acc[8][8] = {};
  for (int k0 = kbase; k0 < kbase + 256; k0 += 16) {
#pragma unroll
    for (int l = 0; l < 2; ++l) {
      int f = tid + l * 256;
      int row = f >> 2, kc = (f & 3) * 4;
      float4 va = *(const float4*)(O + (size_t)(i0 + row) * DOUT + k0 + kc);
      As[kc + 0][row] = va.x; As[kc + 1][row] = va.y;
      As[kc + 2][row] = va.z; As[kc + 3][row] = va.w;
      int kr = f >> 5, c4 = (f & 31) * 4;
      float4 vb = *(const float4*)(wo + (size_t)(k0 + kr) * DIN + n0 + c4);
      *(float4*)&Bs[kr][c4] = vb;
    }
    __syncthreads();
    mm_inner16(As, Bs, acc, tx, ty);
    __syncthreads();
  }
#pragma unroll
  for (int m = 0; m < 8; ++m)
#pragma unroll
    for (int n = 0; n < 8; ++n)
      atomicAdd(&YACC[(size_t)(i0 + ty * 8 + m) * DIN + n0 + tx * 8 + n], acc[m][n]);
}

// ---------------- bias + residual + LayerNorm ----------------
__global__ __launch_bounds__(256) void k_ln(const float* __restrict__ YACC,
                                            const float* __restrict__ x,
                                            const float* __restrict__ wo_b,
                                            const float* __restrict__ g,
                                            const float* __restrict__ b,
                                            float* __restrict__ y) {
  const int i = blockIdx.x;
  const int tid = threadIdx.x;
  float v[3];
#pragma unroll
  for (int t = 0; t < 3; ++t) {
    int cc = tid + t * 256;
    v[t] = YACC[(size_t)i * DIN + cc] + wo_b[cc] + x[(size_t)i * DIN + cc];
  }
  __shared__ float red[256];
  red[tid] = v[0] + v[1] + v[2];
  __syncthreads();
  for (int s = 128; s > 0; s >>= 1) {
    if (tid < s) red[tid] += red[tid + s];
    __syncthreads();
  }
  const float mu = red[0] * (1.0f / DIN);
  __syncthreads();
  float q = 0.f;
#pragma unroll
  for (int t = 0; t < 3; ++t) {
    float d = v[t] - mu;
    q += d * d;
  }
  red[tid] = q;
  __syncthreads();
  for (int s = 128; s > 0; s >>= 1) {
    if (tid < s) red[tid] += red[tid + s];
    __syncthreads();
  }
  const float rs = rsqrtf(red[0] * (1.0f / DIN) + EPSF);
#pragma unroll
  for (int t = 0; t < 3; ++t) {
    int cc = tid + t * 256;
    y[(size_t)i * DIN + cc] = (v[t] - mu) * rs * g[cc] + b[cc];
  }
}

extern "C" void kernel_launch(void* const* d_in, const int* in_sizes, int n_in,
                              void* d_out, int out_size, void* d_ws, size_t ws_size,
                              hipStream_t stream) {
  (void)in_sizes; (void)n_in; (void)out_size; (void)ws_size;
  const float* x       = (const float*)d_in[0];
  const int*   batch   = (const int*)d_in[1];
  const float* motif   = (const float*)d_in[2];
  const float* wq_w    = (const float*)d_in[3];
  const float* wq_b    = (const float*)d_in[4];
  const float* wk_w    = (const float*)d_in[5];
  const float* wk_b    = (const float*)d_in[6];
  const float* wv_w    = (const float*)d_in[7];
  const float* wv_b    = (const float*)d_in[8];
  const float* wo_w    = (const float*)d_in[9];
  const float* wo_b    = (const float*)d_in[10];
  const float* ln_g    = (const float*)d_in[11];
  const float* ln_b    = (const float*)d_in[12];
  const float* alpha_p = (const float*)d_in[13];
  const float* beta_p  = (const float*)d_in[14];
  const float* gq_w    = (const float*)d_in[15];
  const float* gq_b    = (const float*)d_in[16];
  const float* gk_w    = (const float*)d_in[17];
  const float* gk_b    = (const float*)d_in[18];
  const float* headW   = (const float*)d_in[19];

  float* y    = (float*)d_out;
  float* ATTN = (float*)d_out + (size_t)NN * DIN;
  float* ws   = (float*)d_ws;
  float* QKV  = ws + OFF_QKV;
  float* GQ   = ws + OFF_GQ;
  float* GK   = ws + OFF_GK;
  float* MX   = ws + OFF_MX;
  float* INV  = ws + OFF_INV;
  float* O    = ws + OFF_O;
  float* YACC = ws + OFF_YACC;

  // zero O + YACC (3670016 floats = 917504 float4 = 3584 * 256)
  k_zero<<<3584, 256, 0, stream>>>((float4*)(ws + OFF_O));
  k_qkv<<<dim3(24, 16), 256, 0, stream>>>(x, wq_w, wk_w, wv_w, wq_b, wk_b, wv_b, QKV);
  k_gates<<<NN, 256, 0, stream>>>(QKV, gq_w, gq_b, gk_w, gk_b, GQ, GK);
  k_scores<<<dim3(16, 16, NH), 256, 0, stream>>>(QKV, batch, ATTN);
  k_assemble<<<dim3(NN / TS, NN / TS), 256, 0, stream>>>(ATTN, motif, GQ, GK, headW,
                                                         alpha_p, beta_p);
  k_stats<<<NH * NN, 256, 0, stream>>>(ATTN, MX, INV);
  k_pv<<<dim3(4, 16, NH), 256, 0, stream>>>(ATTN, QKV, MX, INV, O);
  k_outproj<<<dim3(6, 16, 4), 256, 0, stream>>>(O, wo_w, YACC);
  k_ln<<<NN, 256, 0, stream>>>(YACC, x, wo_b, ln_g, ln_b, y);
}

// Round 4
// 826.271 us; speedup vs baseline: 1.4688x; 1.4688x over previous
//
#include <hip/hip_runtime.h>

#define NN    2048
#define DIN   768
#define DOUT  1024
#define NH    8
#define HD    128
#define SCALEF 0.08838834764831845f
#define NEGF  (-1.0e9f)
#define EPSF  1e-5f

typedef __attribute__((ext_vector_type(4))) float f32x4;
typedef __attribute__((ext_vector_type(8))) short bf16x8;

// workspace layout (float-slot offsets)
#define OFF_O    0                         // 2,097,152 f32
#define OFF_YACC 2097152                   // 1,572,864 f32  (zero region = [0, 3670016))
#define OFF_Q    3670016                   // 2,097,152 bf16 [8][2048][128]
#define OFF_K    4718592
#define OFF_VB   5767168                   // 2,097,152 bf16 [2048][1024]
#define OFF_VT   6815744                   // 2,097,152 bf16 [8][128][2048]
#define OFF_XB   7864320                   // 1,572,864 bf16 [2048][768]
#define OFF_WT   8650752                   // 2,359,296 bf16 [3][1024][768]
#define OFF_GQ   9830400
#define OFF_GK   9846784
#define OFF_MX   9863168
#define OFF_INV  9879552

__device__ __forceinline__ short f2bf(float f) {
  union { float f; unsigned u; } v; v.f = f;
  unsigned r = v.u + 0x7FFF + ((v.u >> 16) & 1);
  return (short)(r >> 16);
}
__device__ __forceinline__ float bf2f(short s) {
  union { unsigned u; float f; } v; v.u = ((unsigned)(unsigned short)s) << 16;
  return v.f;
}

// ---------------- zero O + YACC ----------------
__global__ __launch_bounds__(256) void k_zero(float4* __restrict__ p) {
  p[(size_t)blockIdx.x * 256 + threadIdx.x] = float4{0.f, 0.f, 0.f, 0.f};
}

// ---------------- cast x -> bf16 ----------------
__global__ __launch_bounds__(256) void k_cast_x(const float* __restrict__ x,
                                                short* __restrict__ xb) {
  int idx = blockIdx.x * 256 + threadIdx.x;  // 393216 float4s
  float4 v = ((const float4*)x)[idx];
  union { short s[4]; float2 f; } u;
  u.s[0] = f2bf(v.x); u.s[1] = f2bf(v.y); u.s[2] = f2bf(v.z); u.s[3] = f2bf(v.w);
  ((float2*)xb)[idx] = u.f;
}

// ---------------- transpose+cast W[768][1024] -> Wt[z][1024][768] bf16 ----------------
__global__ __launch_bounds__(256) void k_w_cast_t(const float* __restrict__ wq,
                                                  const float* __restrict__ wk,
                                                  const float* __restrict__ wv,
                                                  short* __restrict__ Wt) {
  const int c0 = blockIdx.x * 64, k0 = blockIdx.y * 64, z = blockIdx.z;
  const float* Wm = (z == 0) ? wq : (z == 1) ? wk : wv;
  __shared__ float t[64][65];
  const int tid = threadIdx.x;
#pragma unroll
  for (int l = 0; l < 4; ++l) {
    int f = tid + l * 256;
    int r = f >> 4, c4 = (f & 15) * 4;
    *(float4*)&t[r][c4] = *(const float4*)(Wm + (size_t)(k0 + r) * DOUT + c0 + c4);
  }
  __syncthreads();
  int r2 = tid >> 2, q = tid & 3;
  union { short s[16]; float4 f[2]; } buf;
#pragma unroll
  for (int jj = 0; jj < 16; ++jj) buf.s[jj] = f2bf(t[q * 16 + jj][r2]);
  short* dst = Wt + (size_t)z * (1024 * 768) + (size_t)(c0 + r2) * 768 + k0 + q * 16;
  ((float4*)dst)[0] = buf.f[0];
  ((float4*)dst)[1] = buf.f[1];
}

// ---------------- QKV projection (bf16 MFMA): writes Qb/Kb [h][n][d], Vb [n][1024] ----------------
__global__ __launch_bounds__(256) void k_qkv(const short* __restrict__ xb,
                                             const short* __restrict__ Wt,
                                             const float* __restrict__ bq,
                                             const float* __restrict__ bk,
                                             const float* __restrict__ bv,
                                             short* __restrict__ Qb,
                                             short* __restrict__ Kb,
                                             short* __restrict__ Vb) {
  const int n0 = blockIdx.x * 128;  // 0..3071
  const int i0 = blockIdx.y * 128;
  const int mat = n0 >> 10;
  const int cl = n0 & 1023;
  const float* bias = (mat == 0) ? bq : (mat == 1) ? bk : bv;
  const short* Wm = Wt + (size_t)mat * (1024 * 768);
  const int tid = threadIdx.x, lane = tid & 63, wave = tid >> 6;
  const int ln = lane & 15, quad = lane >> 4, q8 = quad * 8;
  f32x4 acc[2][8];
#pragma unroll
  for (int a = 0; a < 2; ++a)
#pragma unroll
    for (int b = 0; b < 8; ++b) acc[a][b] = (f32x4){0.f, 0.f, 0.f, 0.f};
  const short* a0 = xb + (size_t)(i0 + 32 * wave + ln) * DIN + q8;
  const short* a1 = a0 + 16 * DIN;
  const short* bp = Wm + (size_t)(cl + ln) * DIN + q8;
  for (int ks = 0; ks < 24; ++ks) {
    bf16x8 A0 = *(const bf16x8*)(a0 + 32 * ks);
    bf16x8 A1 = *(const bf16x8*)(a1 + 32 * ks);
#pragma unroll
    for (int nt = 0; nt < 8; ++nt) {
      bf16x8 B = *(const bf16x8*)(bp + (size_t)nt * (16 * DIN) + 32 * ks);
      acc[0][nt] = __builtin_amdgcn_mfma_f32_16x16x32_bf16(A0, B, acc[0][nt], 0, 0, 0);
      acc[1][nt] = __builtin_amdgcn_mfma_f32_16x16x32_bf16(A1, B, acc[1][nt], 0, 0, 0);
    }
  }
#pragma unroll
  for (int rt = 0; rt < 2; ++rt)
#pragma unroll
    for (int nt = 0; nt < 8; ++nt) {
      int cg = cl + 16 * nt + ln;
      float bb = bias[cg];
#pragma unroll
      for (int reg = 0; reg < 4; ++reg) {
        int rr = i0 + 32 * wave + 16 * rt + quad * 4 + reg;
        short s = f2bf(acc[rt][nt][reg] + bb);
        if (mat == 2) {
          Vb[(size_t)rr * 1024 + cg] = s;
        } else {
          int h = cg >> 7, d = cg & 127;
          (mat == 0 ? Qb : Kb)[((size_t)h * NN + rr) * HD + d] = s;
        }
      }
    }
}

// ---------------- transpose Vb -> Vt[h][d][n] bf16 ----------------
__global__ __launch_bounds__(256) void k_v_t(const short* __restrict__ Vb,
                                             short* __restrict__ Vt) {
  const int i0 = blockIdx.x * 64, h = blockIdx.y;
  __shared__ __align__(16) short t[64][136];
  const int tid = threadIdx.x;
#pragma unroll
  for (int l = 0; l < 2; ++l) {
    int f = tid + l * 256;
    int r = f >> 3, c8 = (f & 7) * 16;
    const short* src = Vb + (size_t)(i0 + r) * 1024 + h * HD + c8;
    *(bf16x8*)&t[r][c8] = *(const bf16x8*)src;
    *(bf16x8*)&t[r][c8 + 8] = *(const bf16x8*)(src + 8);
  }
  __syncthreads();
  int d = tid >> 1, half = tid & 1;
  union { short s[32]; float4 f[4]; } buf;
#pragma unroll
  for (int ii = 0; ii < 32; ++ii) buf.s[ii] = t[32 * half + ii][d];
  short* dst = Vt + (size_t)h * (HD * NN) + (size_t)d * NN + i0 + 32 * half;
#pragma unroll
  for (int q = 0; q < 4; ++q) ((float4*)dst)[q] = buf.f[q];
}

// ---------------- gating from bf16 Q/K ----------------
__global__ __launch_bounds__(256) void k_gates(const short* __restrict__ Qb,
                                               const short* __restrict__ Kb,
                                               const float* __restrict__ gqw,
                                               const float* __restrict__ gqb,
                                               const float* __restrict__ gkw,
                                               const float* __restrict__ gkb,
                                               float* __restrict__ GQ,
                                               float* __restrict__ GK) {
  const int i = blockIdx.x;
  const int tid = threadIdx.x;
  float aq[NH] = {}, ak[NH] = {};
  for (int d = tid; d < DOUT; d += 256) {
    int h = d >> 7, dd = d & 127;
    float qv = bf2f(Qb[((size_t)h * NN + i) * HD + dd]);
    float kv = bf2f(Kb[((size_t)h * NN + i) * HD + dd]);
#pragma unroll
    for (int h2 = 0; h2 < NH; ++h2) {
      aq[h2] = fmaf(qv, gqw[d * NH + h2], aq[h2]);
      ak[h2] = fmaf(kv, gkw[d * NH + h2], ak[h2]);
    }
  }
  __shared__ float red8[NH][256];
#pragma unroll
  for (int h = 0; h < NH; ++h) red8[h][tid] = aq[h];
  __syncthreads();
  for (int s = 128; s > 0; s >>= 1) {
    if (tid < s) {
#pragma unroll
      for (int h = 0; h < NH; ++h) red8[h][tid] += red8[h][tid + s];
    }
    __syncthreads();
  }
  if (tid < NH) GQ[i * NH + tid] = tanhf(red8[tid][0] + gqb[tid]);
  __syncthreads();
#pragma unroll
  for (int h = 0; h < NH; ++h) red8[h][tid] = ak[h];
  __syncthreads();
  for (int s = 128; s > 0; s >>= 1) {
    if (tid < s) {
#pragma unroll
      for (int h = 0; h < NH; ++h) red8[h][tid] += red8[h][tid + s];
    }
    __syncthreads();
  }
  if (tid < NH) GK[i * NH + tid] = tanhf(red8[tid][0] + gkb[tid]);
}

// ---------------- fused scores + assemble (MFMA, tile-pair) ----------------
__global__ __launch_bounds__(256) void k_sa(const short* __restrict__ Qb,
                                            const short* __restrict__ Kb,
                                            const int* __restrict__ batch,
                                            const float* __restrict__ motif,
                                            const float* __restrict__ GQ,
                                            const float* __restrict__ GK,
                                            const float* __restrict__ Wh,
                                            const float* __restrict__ alpha_p,
                                            const float* __restrict__ beta_p,
                                            float* __restrict__ ATTN) {
  const int bi = blockIdx.y, bj = blockIdx.x;
  if (bj < bi) return;
  const int i0 = bi * 32, j0 = bj * 32;
  const int tid = threadIdx.x, lane = tid & 63, wave = tid >> 6;
  const int wr = wave >> 1, wc = wave & 1;
  const int ln = lane & 15, quad = lane >> 4, q8 = quad * 8;
  __shared__ float SijM[32][33], SjiM[32][33], mo1[32][33], mo2[32][33];
  __shared__ float Lg[4][32][8];  // 0 gq@i0, 1 gq@j0, 2 gk@i0, 3 gk@j0
  __shared__ float sW[64];
  __shared__ int Lb[2][32];
  for (int f = tid; f < 1024; f += 256) {
    int set = f >> 8;
    int r = (f >> 3) & 31, h = f & 7;
    const float* src = (set < 2) ? GQ : GK;
    int base = (set & 1) ? j0 : i0;
    Lg[set][r][h] = src[(base + r) * NH + h];
  }
  if (tid < 64) sW[tid] = Wh[tid];
  if (tid < 32) Lb[0][tid] = batch[i0 + tid];
  else if (tid < 64) Lb[1][tid - 32] = batch[j0 + tid - 32];
  const float alpha = alpha_p[0], beta = beta_p[0];

  f32x4 accIJ[8], accJI[8];
#pragma unroll
  for (int h = 0; h < 8; ++h) {
    accIJ[h] = (f32x4){0.f, 0.f, 0.f, 0.f};
    accJI[h] = (f32x4){0.f, 0.f, 0.f, 0.f};
  }
  const int rQi = i0 + 16 * wr + ln, rQj = j0 + 16 * wr + ln;
  const int rKj = j0 + 16 * wc + ln, rKi = i0 + 16 * wc + ln;
#pragma unroll
  for (int h = 0; h < NH; ++h) {
    const short* pQi = Qb + ((size_t)h * NN + rQi) * HD + q8;
    const short* pQj = Qb + ((size_t)h * NN + rQj) * HD + q8;
    const short* pKj = Kb + ((size_t)h * NN + rKj) * HD + q8;
    const short* pKi = Kb + ((size_t)h * NN + rKi) * HD + q8;
#pragma unroll
    for (int ks = 0; ks < 4; ++ks) {
      bf16x8 a1 = *(const bf16x8*)(pQi + 32 * ks);
      bf16x8 b1 = *(const bf16x8*)(pKj + 32 * ks);
      accIJ[h] = __builtin_amdgcn_mfma_f32_16x16x32_bf16(a1, b1, accIJ[h], 0, 0, 0);
      bf16x8 a2 = *(const bf16x8*)(pQj + 32 * ks);
      bf16x8 b2 = *(const bf16x8*)(pKi + 32 * ks);
      accJI[h] = __builtin_amdgcn_mfma_f32_16x16x32_bf16(a2, b2, accJI[h], 0, 0, 0);
    }
  }
  __syncthreads();  // preload visible
  // mask + scale in place
  {
    int bA = Lb[1][16 * wc + ln];  // col batch for IJ tile
    int bB = Lb[0][16 * wc + ln];  // col batch for JI tile
#pragma unroll
    for (int reg = 0; reg < 4; ++reg) {
      int mIJ = Lb[0][16 * wr + quad * 4 + reg];
      int mJI = Lb[1][16 * wr + quad * 4 + reg];
#pragma unroll
      for (int h = 0; h < NH; ++h) {
        accIJ[h][reg] = (mIJ == bA) ? accIJ[h][reg] * SCALEF : NEGF;
        accJI[h][reg] = (mJI == bB) ? accJI[h][reg] * SCALEF : NEGF;
      }
    }
  }
  const int rA = 16 * wr + quad * 4;  // +reg
  const int cA = 16 * wc + ln;
  const int mr = tid >> 3, mc = (tid & 7) * 4;
  for (int h = 0; h < NH; ++h) {
    __syncthreads();
#pragma unroll
    for (int reg = 0; reg < 4; ++reg) {
      SijM[rA + reg][cA] = accIJ[h][reg];
      SjiM[rA + reg][cA] = accJI[h][reg];
    }
    *(float4*)&mo1[mr][mc] = *(const float4*)(motif + ((size_t)h * NN + j0 + mr) * NN + i0 + mc);
    *(float4*)&mo2[mr][mc] = *(const float4*)(motif + ((size_t)h * NN + i0 + mr) * NN + j0 + mc);
    __syncthreads();
#pragma unroll
    for (int reg = 0; reg < 4; ++reg) {
      int r = rA + reg;
      float s = accIJ[h][reg];
      float hm = 0.f;
#pragma unroll
      for (int h2 = 0; h2 < NH; ++h2) hm = fmaf(accIJ[h2][reg], sW[h2 * NH + h], hm);
      float o = s * (1.f + Lg[0][r][h] + Lg[3][cA][h]) + alpha * SjiM[cA][r] +
                beta * mo1[cA][r] + hm;
      ATTN[((size_t)h * NN + i0 + r) * NN + j0 + cA] = o;
    }
    if (bi != bj) {
#pragma unroll
      for (int reg = 0; reg < 4; ++reg) {
        int r = rA + reg;
        float s = accJI[h][reg];
        float hm = 0.f;
#pragma unroll
        for (int h2 = 0; h2 < NH; ++h2) hm = fmaf(accJI[h2][reg], sW[h2 * NH + h], hm);
        float o = s * (1.f + Lg[1][r][h] + Lg[2][cA][h]) + alpha * SijM[cA][r] +
                  beta * mo2[cA][r] + hm;
        ATTN[((size_t)h * NN + j0 + r) * NN + i0 + cA] = o;
      }
    }
  }
}

// ---------------- softmax stats per row ----------------
__global__ __launch_bounds__(256) void k_stats(const float* __restrict__ ATTN,
                                               float* __restrict__ MX,
                                               float* __restrict__ INVS) {
  const int row = blockIdx.x;
  const int tid = threadIdx.x;
  const float4* p = (const float4*)(ATTN + (size_t)row * NN);
  float4 a = p[tid], b = p[tid + 256];
  float m = fmaxf(fmaxf(fmaxf(a.x, a.y), fmaxf(a.z, a.w)),
                  fmaxf(fmaxf(b.x, b.y), fmaxf(b.z, b.w)));
  __shared__ float red[256];
  red[tid] = m; __syncthreads();
  for (int s = 128; s > 0; s >>= 1) {
    if (tid < s) red[tid] = fmaxf(red[tid], red[tid + s]);
    __syncthreads();
  }
  m = red[0];
  __syncthreads();
  float sum = expf(a.x - m) + expf(a.y - m) + expf(a.z - m) + expf(a.w - m) +
              expf(b.x - m) + expf(b.y - m) + expf(b.z - m) + expf(b.w - m);
  red[tid] = sum; __syncthreads();
  for (int s = 128; s > 0; s >>= 1) {
    if (tid < s) red[tid] += red[tid + s];
    __syncthreads();
  }
  if (tid == 0) {
    MX[row] = m;
    INVS[row] = 1.0f / red[0];
  }
}

// ---------------- P@V (bf16 MFMA, on-the-fly softmax, K-split 4 + atomics) ----------------
__global__ __launch_bounds__(256) void k_pv(const float* __restrict__ ATTN,
                                            const short* __restrict__ Vt,
                                            const float* __restrict__ MX,
                                            const float* __restrict__ INVS,
                                            float* __restrict__ O) {
  const int i0 = blockIdx.x * 64;
  const int j0 = blockIdx.y * 512;
  const int h = blockIdx.z;
  const int tid = threadIdx.x, lane = tid & 63, wave = tid >> 6;
  const int ln = lane & 15, quad = lane >> 4, q8 = quad * 8;
  __shared__ __align__(16) short Vl[2][128][40];
  const int row = i0 + 16 * wave + ln;
  const size_t rflat = (size_t)h * NN + row;
  const float mx = MX[rflat], inv = INVS[rflat];
  const float* arow = ATTN + rflat * NN;
  const short* vbase = Vt + (size_t)h * (HD * NN);
  f32x4 acc[8];
#pragma unroll
  for (int nt = 0; nt < 8; ++nt) acc[nt] = (f32x4){0.f, 0.f, 0.f, 0.f};
  // stage 128 d-rows x 32 j-cols: 2 threads per row, 16 shorts per thread
  const int vr = tid >> 1, vh = (tid & 1) * 16;
  *(bf16x8*)&Vl[0][vr][vh] = *(const bf16x8*)(vbase + (size_t)vr * NN + j0 + vh);
  *(bf16x8*)&Vl[0][vr][vh + 8] = *(const bf16x8*)(vbase + (size_t)vr * NN + j0 + vh + 8);
  __syncthreads();
  int buf = 0;
  for (int jk = j0; jk < j0 + 512; jk += 32, buf ^= 1) {
    if (jk + 32 < j0 + 512) {
      *(bf16x8*)&Vl[buf ^ 1][vr][vh] =
          *(const bf16x8*)(vbase + (size_t)vr * NN + jk + 32 + vh);
      *(bf16x8*)&Vl[buf ^ 1][vr][vh + 8] =
          *(const bf16x8*)(vbase + (size_t)vr * NN + jk + 32 + vh + 8);
    }
    float4 u1 = *(const float4*)(arow + jk + q8);
    float4 u2 = *(const float4*)(arow + jk + q8 + 4);
    bf16x8 a;
    a[0] = f2bf(__expf(u1.x - mx) * inv);
    a[1] = f2bf(__expf(u1.y - mx) * inv);
    a[2] = f2bf(__expf(u1.z - mx) * inv);
    a[3] = f2bf(__expf(u1.w - mx) * inv);
    a[4] = f2bf(__expf(u2.x - mx) * inv);
    a[5] = f2bf(__expf(u2.y - mx) * inv);
    a[6] = f2bf(__expf(u2.z - mx) * inv);
    a[7] = f2bf(__expf(u2.w - mx) * inv);
#pragma unroll
    for (int nt = 0; nt < 8; ++nt) {
      bf16x8 b = *(const bf16x8*)&Vl[buf][16 * nt + ln][q8];
      acc[nt] = __builtin_amdgcn_mfma_f32_16x16x32_bf16(a, b, acc[nt], 0, 0, 0);
    }
    __syncthreads();
  }
#pragma unroll
  for (int nt = 0; nt < 8; ++nt)
#pragma unroll
    for (int reg = 0; reg < 4; ++reg) {
      int rr = i0 + 16 * wave + quad * 4 + reg;
      atomicAdd(&O[(size_t)rr * DOUT + h * HD + 16 * nt + ln], acc[nt][reg]);
    }
}

// ---------------- out-proj SGEMM f32 (K-split + atomics) ----------------
__device__ __forceinline__ void mm_inner16(const float (*As)[132],
                                           const float (*Bs)[132],
                                           float (&acc)[8][8], int tx, int ty) {
#pragma unroll
  for (int k = 0; k < 16; ++k) {
    float a[8], b[8];
    *(float4*)&a[0] = *(const float4*)&As[k][ty * 8];
    *(float4*)&a[4] = *(const float4*)&As[k][ty * 8 + 4];
    *(float4*)&b[0] = *(const float4*)&Bs[k][tx * 8];
    *(float4*)&b[4] = *(const float4*)&Bs[k][tx * 8 + 4];
#pragma unroll
    for (int m = 0; m < 8; ++m)
#pragma unroll
      for (int n = 0; n < 8; ++n)
        acc[m][n] = fmaf(a[m], b[n], acc[m][n]);
  }
}

__global__ __launch_bounds__(256) void k_outproj(const float* __restrict__ O,
                                                 const float* __restrict__ wo,
                                                 float* __restrict__ YACC) {
  const int n0 = blockIdx.x * 128;
  const int i0 = blockIdx.y * 128;
  const int kbase = blockIdx.z * 256;
  __shared__ __align__(16) float As[16][132];
  __shared__ __align__(16) float Bs[16][132];
  const int tid = threadIdx.x;
  const int tx = tid & 15, ty = tid >> 4;
  float acc[8][8] = {};
  for (int k0 = kbase; k0 < kbase + 256; k0 += 16) {
#pragma unroll
    for (int l = 0; l < 2; ++l) {
      int f = tid + l * 256;
      int row = f >> 2, kc = (f & 3) * 4;
      float4 va = *(const float4*)(O + (size_t)(i0 + row) * DOUT + k0 + kc);
      As[kc + 0][row] = va.x; As[kc + 1][row] = va.y;
      As[kc + 2][row] = va.z; As[kc + 3][row] = va.w;
      int kr = f >> 5, c4 = (f & 31) * 4;
      float4 vb = *(const float4*)(wo + (size_t)(k0 + kr) * DIN + n0 + c4);
      *(float4*)&Bs[kr][c4] = vb;
    }
    __syncthreads();
    mm_inner16(As, Bs, acc, tx, ty);
    __syncthreads();
  }
#pragma unroll
  for (int m = 0; m < 8; ++m)
#pragma unroll
    for (int n = 0; n < 8; ++n)
      atomicAdd(&YACC[(size_t)(i0 + ty * 8 + m) * DIN + n0 + tx * 8 + n], acc[m][n]);
}

// ---------------- bias + residual + LayerNorm ----------------
__global__ __launch_bounds__(256) void k_ln(const float* __restrict__ YACC,
                                            const float* __restrict__ x,
                                            const float* __restrict__ wo_b,
                                            const float* __restrict__ g,
                                            const float* __restrict__ b,
                                            float* __restrict__ y) {
  const int i = blockIdx.x;
  const int tid = threadIdx.x;
  float v[3];
#pragma unroll
  for (int t = 0; t < 3; ++t) {
    int cc = tid + t * 256;
    v[t] = YACC[(size_t)i * DIN + cc] + wo_b[cc] + x[(size_t)i * DIN + cc];
  }
  __shared__ float red[256];
  red[tid] = v[0] + v[1] + v[2];
  __syncthreads();
  for (int s = 128; s > 0; s >>= 1) {
    if (tid < s) red[tid] += red[tid + s];
    __syncthreads();
  }
  const float mu = red[0] * (1.0f / DIN);
  __syncthreads();
  float q = 0.f;
#pragma unroll
  for (int t = 0; t < 3; ++t) {
    float d = v[t] - mu;
    q += d * d;
  }
  red[tid] = q;
  __syncthreads();
  for (int s = 128; s > 0; s >>= 1) {
    if (tid < s) red[tid] += red[tid + s];
    __syncthreads();
  }
  const float rs = rsqrtf(red[0] * (1.0f / DIN) + EPSF);
#pragma unroll
  for (int t = 0; t < 3; ++t) {
    int cc = tid + t * 256;
    y[(size_t)i * DIN + cc] = (v[t] - mu) * rs * g[cc] + b[cc];
  }
}

extern "C" void kernel_launch(void* const* d_in, const int* in_sizes, int n_in,
                              void* d_out, int out_size, void* d_ws, size_t ws_size,
                              hipStream_t stream) {
  (void)in_sizes; (void)n_in; (void)out_size; (void)ws_size;
  const float* x       = (const float*)d_in[0];
  const int*   batch   = (const int*)d_in[1];
  const float* motif   = (const float*)d_in[2];
  const float* wq_w    = (const float*)d_in[3];
  const float* wq_b    = (const float*)d_in[4];
  const float* wk_w    = (const float*)d_in[5];
  const float* wk_b    = (const float*)d_in[6];
  const float* wv_w    = (const float*)d_in[7];
  const float* wv_b    = (const float*)d_in[8];
  const float* wo_w    = (const float*)d_in[9];
  const float* wo_b    = (const float*)d_in[10];
  const float* ln_g    = (const float*)d_in[11];
  const float* ln_b    = (const float*)d_in[12];
  const float* alpha_p = (const float*)d_in[13];
  const float* beta_p  = (const float*)d_in[14];
  const float* gq_w    = (const float*)d_in[15];
  const float* gq_b    = (const float*)d_in[16];
  const float* gk_w    = (const float*)d_in[17];
  const float* gk_b    = (const float*)d_in[18];
  const float* headW   = (const float*)d_in[19];

  float* y    = (float*)d_out;
  float* ATTN = (float*)d_out + (size_t)NN * DIN;
  float* ws   = (float*)d_ws;
  float* O    = ws + OFF_O;
  float* YACC = ws + OFF_YACC;
  short* Qb   = (short*)(ws + OFF_Q);
  short* Kb   = (short*)(ws + OFF_K);
  short* Vb   = (short*)(ws + OFF_VB);
  short* Vt   = (short*)(ws + OFF_VT);
  short* xb   = (short*)(ws + OFF_XB);
  short* Wt   = (short*)(ws + OFF_WT);
  float* GQ   = ws + OFF_GQ;
  float* GK   = ws + OFF_GK;
  float* MX   = ws + OFF_MX;
  float* INV  = ws + OFF_INV;

  k_zero<<<3584, 256, 0, stream>>>((float4*)(ws + OFF_O));
  k_cast_x<<<1536, 256, 0, stream>>>(x, xb);
  k_w_cast_t<<<dim3(16, 12, 3), 256, 0, stream>>>(wq_w, wk_w, wv_w, Wt);
  k_qkv<<<dim3(24, 16), 256, 0, stream>>>(xb, Wt, wq_b, wk_b, wv_b, Qb, Kb, Vb);
  k_v_t<<<dim3(32, 8), 256, 0, stream>>>(Vb, Vt);
  k_gates<<<NN, 256, 0, stream>>>(Qb, Kb, gq_w, gq_b, gk_w, gk_b, GQ, GK);
  k_sa<<<dim3(64, 64), 256, 0, stream>>>(Qb, Kb, batch, motif, GQ, GK, headW,
                                         alpha_p, beta_p, ATTN);
  k_stats<<<NH * NN, 256, 0, stream>>>(ATTN, MX, INV);
  k_pv<<<dim3(32, 4, NH), 256, 0, stream>>>(ATTN, Vt, MX, INV, O);
  k_outproj<<<dim3(6, 16, 4), 256, 0, stream>>>(O, wo_w, YACC);
  k_ln<<<NN, 256, 0, stream>>>(YACC, x, wo_b, ln_g, ln_b, y);
}